// Round 8
// baseline (1475.793 us; speedup 1.0000x reference)
//
#include <hip/hip_runtime.h>
#include <hip/hip_bf16.h>
#include <cstddef>

// ---------------- problem constants ----------------
constexpr int cN_LOW  = 20000;
constexpr int cN_HIGH = 150000;
constexpr int cSEQ = 25;
constexpr int cHIN = 25;
constexpr int cHHID = 25;
constexpr int cENC = 32;
constexpr int cHIGH_IN = 7;
constexpr int cD = 16;
constexpr int cNL = 5;
constexpr int cE_L2H = 1350000;
constexpr int cE_HH = 1200000;
constexpr float cEPS = 1e-5f;
constexpr float cSLOPE = 0.2f;
constexpr float INV_NLOW  = 1.0f / (float)cN_LOW;
constexpr float INV_NHIGH = 1.0f / (float)cN_HIGH;

constexpr int cHSP = 628;     // padded hs row stride (16B-aligned rows)

// scan geometry
constexpr int SC_ELEM = 1024;
constexpr int SC_NB   = (cN_HIGH + SC_ELEM - 1) / SC_ELEM;     // 147
static_assert(SC_NB <= 256, "top scan assumes <=256 partials");

// ---------------- workspace layout (4-byte element offsets) ----------------
constexpr size_t OFF_HS   = 0;                                   // [N_LOW*628]
constexpr size_t SZ_HS    = (size_t)cN_LOW * cHSP;
constexpr size_t OFF_AGG  = 0;                                   // alias (hs dead after k_dense)
constexpr size_t OFF_ENC  = OFF_HS + SZ_HS;                      // [N_LOW*32]
constexpr size_t SZ_ENC   = (size_t)cN_LOW * cENC;
constexpr size_t OFF_XA   = OFF_ENC + SZ_ENC;
constexpr size_t OFF_XB   = OFF_XA + (size_t)cN_HIGH * cD;
constexpr size_t OFF_XL   = OFF_XB + (size_t)cN_HIGH * cD;
constexpr size_t OFF_XR   = OFF_XL + (size_t)cN_HIGH * cD;
constexpr size_t OFF_STAT = OFF_XR + (size_t)cN_HIGH * cD;       // [256]
constexpr size_t OFF_RPH  = OFF_STAT + 256;                      // rowptr_hh [N_HIGH+4]
constexpr size_t OFF_SRH  = OFF_RPH + cN_HIGH + 4;               // src_hh [E_HH]
constexpr size_t OFF_RPL  = OFF_SRH + cE_HH;                     // rowptr_l2h [N_HIGH+4]
constexpr size_t OFF_SRL  = OFF_RPL + cN_HIGH + 4;               // src_l2h [E_L2H]
constexpr size_t OFF_CUR  = OFF_SRL + cE_L2H;                    // cursor [N_HIGH]
constexpr size_t OFF_PART = OFF_CUR + cN_HIGH;                   // partials [256]
constexpr size_t OFF_XLB  = OFF_PART + 256;                      // xl bf16 [N_HIGH*16 ushort]

__device__ __forceinline__ float fast_sigmoid(float a) {
  return __builtin_amdgcn_rcpf(1.0f + __expf(-a));
}
__device__ __forceinline__ float fast_tanh(float a) {
  float t = __expf(-2.0f * a);
  return (1.0f - t) * __builtin_amdgcn_rcpf(1.0f + t);
}
__device__ __forceinline__ unsigned int f32_to_bf16_bits(float f) {
  unsigned int u = __float_as_uint(f);
  return (u + 0x7FFFu + ((u >> 16) & 1u)) >> 16;     // RNE
}
__device__ __forceinline__ float bf16_bits_to_f32(unsigned int h) {
  return __uint_as_float(h << 16);
}

// ---------------- GRU kernel ----------------
// Weights in VGPRs (150/thread). r7 showed launch_bounds(256,2) let the
// allocator cap at 128 VGPR and spill; (256,1) allows the ~200 needed.
constexpr int GRU_NODES = 10;
constexpr int GRU_BLOCK = GRU_NODES * cHHID;   // 250

__global__ __launch_bounds__(256, 1)
void k_gru(const float* __restrict__ x_low,
           const float* __restrict__ Wih, const float* __restrict__ Whh,
           const float* __restrict__ bih, const float* __restrict__ bhh,
           float* __restrict__ hs) {
  __shared__ float sx[2][GRU_NODES][cHIN];
  __shared__ float sh[2][GRU_NODES][cHHID];

  int tid = threadIdx.x;
  int nl = tid / cHHID;           // 0..9
  int j  = tid % cHHID;           // 0..24
  int n  = blockIdx.x * GRU_NODES + nl;

  float wr[25], wz[25], wn[25], ur[25], uz[25], un[25];
  #pragma unroll
  for (int i = 0; i < 25; ++i) {
    wr[i] = Wih[j * 25 + i];
    wz[i] = Wih[(25 + j) * 25 + i];
    wn[i] = Wih[(50 + j) * 25 + i];
    ur[i] = Whh[j * 25 + i];
    uz[i] = Whh[(25 + j) * 25 + i];
    un[i] = Whh[(50 + j) * 25 + i];
  }
  float br = bih[j], bz = bih[25 + j], bn2 = bih[50 + j];
  float cr = bhh[j], cz = bhh[25 + j], cn = bhh[50 + j];

  const float* xrow = x_low + (size_t)n * 625;
  float* hrow = hs + (size_t)n * cHSP;
  if (j < 3) hrow[625 + j] = 0.0f;       // zero hs row pad for dense float4 reads

  sh[0][nl][j] = 0.0f;
  sx[0][nl][j] = xrow[j];                // x for t=0
  __syncthreads();

  int p = 0;
  int q = 0;
  for (int t = 0; t < cSEQ; ++t) {
    if (t + 1 < cSEQ) sx[q ^ 1][nl][j] = xrow[(t + 1) * 25 + j];
    float gr = br + cr, gz = bz + cz, gni = bn2, gnh = cn;
    #pragma unroll
    for (int i = 0; i < 25; ++i) {
      float xv = sx[q][nl][i];
      float hv = sh[p][nl][i];
      gr  += wr[i] * xv + ur[i] * hv;
      gz  += wz[i] * xv + uz[i] * hv;
      gni += wn[i] * xv;
      gnh += un[i] * hv;
    }
    float r = fast_sigmoid(gr);
    float z = fast_sigmoid(gz);
    float nn = fast_tanh(gni + r * gnh);
    float hnew = (1.0f - z) * nn + z * sh[p][nl][j];
    sh[p ^ 1][nl][j] = hnew;
    hrow[t * 25 + j] = hnew;
    p ^= 1;
    q ^= 1;
    __syncthreads();
  }
}

// ---------------- dense 625->32 + relu + BN stats ----------------
__global__ __launch_bounds__(256)
void k_dense(const float* __restrict__ hs, const float* __restrict__ W,
             const float* __restrict__ b, float* __restrict__ enc,
             float* __restrict__ statsEnc) {
  __shared__ __align__(16) float sW[cENC * cHSP];    // 80.4 KB
  __shared__ float sstat[2 * cENC];
  int tid = threadIdx.x;
  for (int i = tid; i < cENC * 625; i += 256) {
    int e2 = i / 625, f2 = i % 625;
    sW[e2 * cHSP + f2] = W[i];
  }
  if (tid < cENC * 3) { int e2 = tid / 3; sW[e2 * cHSP + 625 + tid % 3] = 0.0f; }
  if (tid < 2 * cENC) sstat[tid] = 0.0f;
  __syncthreads();

  int e  = tid & 31;
  int g  = tid >> 5;                    // 0..7
  int n0 = blockIdx.x * 32 + g * 4;
  const float4* H0 = (const float4*)(hs + (size_t)(n0 + 0) * cHSP);
  const float4* H1 = (const float4*)(hs + (size_t)(n0 + 1) * cHSP);
  const float4* H2 = (const float4*)(hs + (size_t)(n0 + 2) * cHSP);
  const float4* H3 = (const float4*)(hs + (size_t)(n0 + 3) * cHSP);
  const float4* W4 = (const float4*)(sW + (size_t)e * cHSP);
  float a0 = 0.0f, a1 = 0.0f, a2 = 0.0f, a3 = 0.0f;
  #pragma unroll 2
  for (int f = 0; f < cHSP / 4; ++f) {
    float4 w = W4[f];
    float4 h0 = H0[f], h1 = H1[f], h2 = H2[f], h3 = H3[f];
    a0 += w.x * h0.x + w.y * h0.y + w.z * h0.z + w.w * h0.w;
    a1 += w.x * h1.x + w.y * h1.y + w.z * h1.z + w.w * h1.w;
    a2 += w.x * h2.x + w.y * h2.y + w.z * h2.z + w.w * h2.w;
    a3 += w.x * h3.x + w.y * h3.y + w.z * h3.z + w.w * h3.w;
  }
  float bb = b[e];
  float v0 = fmaxf(a0 + bb, 0.0f);
  float v1 = fmaxf(a1 + bb, 0.0f);
  float v2 = fmaxf(a2 + bb, 0.0f);
  float v3 = fmaxf(a3 + bb, 0.0f);
  enc[(size_t)(n0 + 0) * cENC + e] = v0;
  enc[(size_t)(n0 + 1) * cENC + e] = v1;
  enc[(size_t)(n0 + 2) * cENC + e] = v2;
  enc[(size_t)(n0 + 3) * cENC + e] = v3;

  float p = v0 + v1 + v2 + v3;
  float q = v0 * v0 + v1 * v1 + v2 * v2 + v3 * v3;
  p += __shfl_down(p, 32);
  q += __shfl_down(q, 32);
  if ((tid & 63) < 32) { atomicAdd(&sstat[e], p); atomicAdd(&sstat[cENC + e], q); }
  __syncthreads();
  if (tid < 2 * cENC) atomicAdd(&statsEnc[tid], sstat[tid]);
}

// ---------------- CSR build ----------------
__global__ void k_hist(const int* __restrict__ dst, int nE, int* __restrict__ cnt) {
  int e = blockIdx.x * 256 + threadIdx.x;
  if (e < nE) atomicAdd(&cnt[dst[e]], 1);
}

__global__ void k_scan_local(const int* __restrict__ deg, int n,
                             int* __restrict__ out, int* __restrict__ partial) {
  int tid = threadIdx.x;
  int base = blockIdx.x * SC_ELEM + tid * 4;
  int4 v = make_int4(0, 0, 0, 0);
  if (base + 3 < n) v = *(const int4*)(deg + base);
  else { int* pv = (int*)&v; for (int k = 0; k < 4; ++k) if (base + k < n) pv[k] = deg[base + k]; }
  int tsum = v.x + v.y + v.z + v.w;
  int lane = tid & 63;
  int inc = tsum;
  #pragma unroll
  for (int o = 1; o < 64; o <<= 1) { int t = __shfl_up(inc, o); if (lane >= o) inc += t; }
  __shared__ int wtot[4];
  if (lane == 63) wtot[tid >> 6] = inc;
  __syncthreads();
  int w = tid >> 6, wbase = 0;
  #pragma unroll
  for (int k = 0; k < 3; ++k) if (k < w) wbase += wtot[k];
  int ebase = wbase + inc - tsum;
  int4 o4;
  o4.x = ebase; o4.y = ebase + v.x; o4.z = o4.y + v.y; o4.w = o4.z + v.z;
  if (base + 3 < n) *(int4*)(out + base) = o4;
  else { int* po = (int*)&o4; for (int k = 0; k < 4; ++k) if (base + k < n) out[base + k] = po[k]; }
  if (tid == 255) partial[blockIdx.x] = wbase + inc;
}

__global__ void k_scan_top(int* __restrict__ partial, int nb, int* __restrict__ total_out) {
  __shared__ int sd[256];
  int tid = threadIdx.x;
  int v = (tid < nb) ? partial[tid] : 0;
  sd[tid] = v;
  __syncthreads();
  for (int off = 1; off < 256; off <<= 1) {
    int t = (tid >= off) ? sd[tid - off] : 0;
    __syncthreads();
    sd[tid] += t;
    __syncthreads();
  }
  if (tid < nb) partial[tid] = sd[tid] - v;
  if (tid == 255) *total_out = sd[255];
}

__global__ void k_scan_add(int* __restrict__ rowptr, const int* __restrict__ partial,
                           int n, int* __restrict__ cursor) {
  int base = blockIdx.x * SC_ELEM + threadIdx.x * 4;
  int add = partial[blockIdx.x];
  if (base + 3 < n) {
    int4 v = *(int4*)(rowptr + base);
    v.x += add; v.y += add; v.z += add; v.w += add;
    *(int4*)(rowptr + base) = v;
    *(int4*)(cursor + base) = v;
  } else {
    for (int k = 0; k < 4; ++k)
      if (base + k < n) { int t = rowptr[base + k] + add; rowptr[base + k] = t; cursor[base + k] = t; }
  }
}

__global__ void k_scatter(const int* __restrict__ src, const int* __restrict__ dst, int nE,
                          int* __restrict__ cursor, int* __restrict__ out) {
  int e = blockIdx.x * 256 + threadIdx.x;
  if (e < nE) {
    int pos = atomicAdd(&cursor[dst[e]], 1);
    out[pos] = src[e];
  }
}

// ---------------- l2h gather via CSR ----------------
__global__ void k_gather_csr(const float* __restrict__ enc, const int* __restrict__ rowptr,
                             const int* __restrict__ srcs, const float* __restrict__ statsEnc,
                             const float* __restrict__ g, const float* __restrict__ bb,
                             float* __restrict__ agg) {
  __shared__ float ssc[cENC], ssh[cENC];
  int tid = threadIdx.x;
  if (tid < cENC) {
    float m = statsEnc[tid] * INV_NLOW;
    float var = statsEnc[cENC + tid] * INV_NLOW - m * m;
    float sc = g[tid] * rsqrtf(var + cEPS);
    ssc[tid] = sc;
    ssh[tid] = bb[tid] - m * sc;
  }
  __syncthreads();
  int c = tid & 31;
  int n = blockIdx.x * 8 + (tid >> 5);
  int lo = rowptr[n], hi = rowptr[n + 1];
  float sum = 0.0f;
  for (int i = lo; i < hi; ++i) {
    int s = srcs[i];
    sum += enc[(size_t)s * cENC + c];
  }
  float deg = (float)(hi - lo);
  agg[(size_t)n * cENC + c] = (ssc[c] * sum + deg * ssh[c]) / fmaxf(deg, 1.0f);
}

// ---------------- down-projection + BN0 stats ----------------
__global__ void k_down(const float* __restrict__ agg,
                       const float* __restrict__ z_std, const float* __restrict__ land,
                       const float* __restrict__ Wrel, const float* __restrict__ brel,
                       const float* __restrict__ Wroot,
                       float* __restrict__ x0, float* __restrict__ stats) {
  __shared__ float sstat[2 * cD];
  __shared__ float sWrel[cD * cENC], sWroot[cD * cHIGH_IN], sbrel[cD];
  int tid = threadIdx.x;
  if (tid < 2 * cD) sstat[tid] = 0.0f;
  for (int i = tid; i < cD * cENC; i += 256) sWrel[i] = Wrel[i];
  if (tid < cD * cHIGH_IN) sWroot[tid] = Wroot[tid];
  if (tid < cD) sbrel[tid] = brel[tid];
  __syncthreads();

  int n = blockIdx.x * 256 + tid;
  bool valid = n < cN_HIGH;
  float a[cENC], zz[cHIGH_IN];
  if (valid) {
    const float4* ar4 = (const float4*)(agg + (size_t)n * cENC);
    #pragma unroll
    for (int k = 0; k < cENC / 4; ++k) {
      float4 t4 = ar4[k];
      a[4*k] = t4.x; a[4*k+1] = t4.y; a[4*k+2] = t4.z; a[4*k+3] = t4.w;
    }
    #pragma unroll
    for (int k = 0; k < 6; ++k) zz[k] = z_std[(size_t)n * 6 + k];
    zz[6] = land[n];
  } else {
    #pragma unroll
    for (int k = 0; k < cENC; ++k) a[k] = 0.0f;
    #pragma unroll
    for (int k = 0; k < cHIGH_IN; ++k) zz[k] = 0.0f;
  }
  int lane = tid & 63;
  #pragma unroll
  for (int d = 0; d < cD; ++d) {
    float acc = sbrel[d];
    #pragma unroll
    for (int k = 0; k < cENC; ++k) acc += a[k] * sWrel[d * cENC + k];
    #pragma unroll
    for (int k = 0; k < cHIGH_IN; ++k) acc += zz[k] * sWroot[d * cHIGH_IN + k];
    if (valid) x0[(size_t)n * cD + d] = acc;
    float v = valid ? acc : 0.0f;
    float s1 = v, s2 = v * v;
    #pragma unroll
    for (int o = 32; o > 0; o >>= 1) { s1 += __shfl_down(s1, o); s2 += __shfl_down(s2, o); }
    if (lane == 0) { atomicAdd(&sstat[d], s1); atomicAdd(&sstat[cD + d], s2); }
  }
  __syncthreads();
  if (tid < 2 * cD) atomicAdd(&stats[tid], sstat[tid]);
}

// ---------------- GAT node transform (also emits bf16 xl rows) ----------------
__global__ void k_transform(const float* __restrict__ xin, const float* __restrict__ stats,
                            const float* __restrict__ g, const float* __restrict__ b,
                            const float* __restrict__ Wl, const float* __restrict__ bl,
                            const float* __restrict__ Wr, const float* __restrict__ br,
                            int applyRelu,
                            float* __restrict__ xl, float* __restrict__ xr,
                            unsigned short* __restrict__ xlb) {
  __shared__ float ssc[cD], ssh[cD], sWl[cD * cD], sWr[cD * cD], sbl[cD], sbr[cD];
  int tid = threadIdx.x;
  if (tid < cD) {
    float m = stats[tid] * INV_NHIGH;
    float v = stats[cD + tid] * INV_NHIGH - m * m;
    float sc = g[tid] * rsqrtf(v + cEPS);
    ssc[tid] = sc;
    ssh[tid] = b[tid] - m * sc;
    sbl[tid] = bl[tid];
    sbr[tid] = br[tid];
  }
  if (tid < cD * cD) { sWl[tid] = Wl[tid]; sWr[tid] = Wr[tid]; }
  __syncthreads();

  int n = blockIdx.x * 256 + tid;
  if (n >= cN_HIGH) return;
  float act[cD];
  const float* xp = xin + (size_t)n * cD;
  #pragma unroll
  for (int d = 0; d < cD; ++d) {
    float v = xp[d] * ssc[d] + ssh[d];
    if (applyRelu) v = fmaxf(v, 0.0f);
    act[d] = v;
  }
  float alv[cD];
  float* xlp = xl + (size_t)n * cD;
  float* xrp = xr + (size_t)n * cD;
  #pragma unroll
  for (int d = 0; d < cD; ++d) {
    float al = sbl[d], ar = sbr[d];
    #pragma unroll
    for (int k = 0; k < cD; ++k) { al += act[k] * sWl[d * cD + k]; ar += act[k] * sWr[d * cD + k]; }
    alv[d] = al;
    xlp[d] = al;
    xrp[d] = ar;
  }
  // pack bf16 row (32 B) for the edge-pass gathers
  uint4 w0, w1;
  unsigned int* pw = (unsigned int*)&w0;
  #pragma unroll
  for (int k = 0; k < 4; ++k)
    pw[k] = f32_to_bf16_bits(alv[2 * k]) | (f32_to_bf16_bits(alv[2 * k + 1]) << 16);
  unsigned int* pw1 = (unsigned int*)&w1;
  #pragma unroll
  for (int k = 0; k < 4; ++k)
    pw1[k] = f32_to_bf16_bits(alv[8 + 2 * k]) | (f32_to_bf16_bits(alv[8 + 2 * k + 1]) << 16);
  uint4* dst = (uint4*)(xlb + (size_t)n * cD);
  dst[0] = w0;
  dst[1] = w1;
}

// ---------------- fused GAT edge pass via CSR (bf16 gathers, 4-way unroll) ----------------
template<int FINAL>
__global__ void k_edge(const float* __restrict__ xl, const float* __restrict__ xr,
                       const unsigned short* __restrict__ xlb,
                       const int* __restrict__ rowptr, const int* __restrict__ srcs,
                       const float* __restrict__ att, const float* __restrict__ bias,
                       const float* __restrict__ pW, const float* __restrict__ pb,
                       float* __restrict__ xout, float* __restrict__ stats,
                       float* __restrict__ out) {
  __shared__ float satt[cD], sbias[cD];
  __shared__ float sstat[2 * cD];
  int tid = threadIdx.x;
  if (tid < cD) { satt[tid] = att[tid]; sbias[tid] = bias[tid]; }
  if (!FINAL && tid < 2 * cD) sstat[tid] = 0.0f;
  __syncthreads();

  int d = tid & 15;
  int n = blockIdx.x * 16 + (tid >> 4);
  float a_d = satt[d];
  float xr_d = xr[(size_t)n * cD + d];
  float xl_self = xl[(size_t)n * cD + d];

  float v = xl_self + xr_d;
  v = v > 0.0f ? v : cSLOPE * v;
  float p = v * a_d;
  p += __shfl_xor(p, 1); p += __shfl_xor(p, 2); p += __shfl_xor(p, 4); p += __shfl_xor(p, 8);
  float ex = __expf(p);
  float denom = ex;
  float num = ex * xl_self;

  int lo = rowptr[n], hi = rowptr[n + 1];
  int i = lo;
  for (; i + 3 < hi; i += 4) {
    int s0 = srcs[i], s1 = srcs[i + 1], s2 = srcs[i + 2], s3 = srcs[i + 3];
    float x0 = bf16_bits_to_f32(xlb[(size_t)s0 * cD + d]);
    float x1 = bf16_bits_to_f32(xlb[(size_t)s1 * cD + d]);
    float x2 = bf16_bits_to_f32(xlb[(size_t)s2 * cD + d]);
    float x3 = bf16_bits_to_f32(xlb[(size_t)s3 * cD + d]);
    float w0 = x0 + xr_d; w0 = w0 > 0.0f ? w0 : cSLOPE * w0;
    float w1 = x1 + xr_d; w1 = w1 > 0.0f ? w1 : cSLOPE * w1;
    float w2 = x2 + xr_d; w2 = w2 > 0.0f ? w2 : cSLOPE * w2;
    float w3 = x3 + xr_d; w3 = w3 > 0.0f ? w3 : cSLOPE * w3;
    float q0 = w0 * a_d, q1 = w1 * a_d, q2 = w2 * a_d, q3 = w3 * a_d;
    q0 += __shfl_xor(q0, 1); q1 += __shfl_xor(q1, 1); q2 += __shfl_xor(q2, 1); q3 += __shfl_xor(q3, 1);
    q0 += __shfl_xor(q0, 2); q1 += __shfl_xor(q1, 2); q2 += __shfl_xor(q2, 2); q3 += __shfl_xor(q3, 2);
    q0 += __shfl_xor(q0, 4); q1 += __shfl_xor(q1, 4); q2 += __shfl_xor(q2, 4); q3 += __shfl_xor(q3, 4);
    q0 += __shfl_xor(q0, 8); q1 += __shfl_xor(q1, 8); q2 += __shfl_xor(q2, 8); q3 += __shfl_xor(q3, 8);
    float e0 = __expf(q0), e1 = __expf(q1), e2c = __expf(q2), e3 = __expf(q3);
    denom += (e0 + e1) + (e2c + e3);
    num += e0 * x0 + e1 * x1 + e2c * x2 + e3 * x3;
  }
  for (; i < hi; ++i) {
    int s = srcs[i];
    float xls = bf16_bits_to_f32(xlb[(size_t)s * cD + d]);
    float w = xls + xr_d;
    w = w > 0.0f ? w : cSLOPE * w;
    float q = w * a_d;
    q += __shfl_xor(q, 1); q += __shfl_xor(q, 2); q += __shfl_xor(q, 4); q += __shfl_xor(q, 8);
    float e2 = __expf(q);
    denom += e2;
    num += e2 * xls;
  }
  float cnt = (float)(hi - lo + 1);
  float res = num / denom / cnt + sbias[d];

  if (FINAL) {
    float t = fmaxf(res, 0.0f) * pW[d];
    t += __shfl_xor(t, 1); t += __shfl_xor(t, 2); t += __shfl_xor(t, 4); t += __shfl_xor(t, 8);
    if (d == 0) out[n] = t + pb[0];
  } else {
    xout[(size_t)n * cD + d] = res;
    float s1 = res, s2 = res * res;
    s1 += __shfl_xor(s1, 16); s2 += __shfl_xor(s2, 16);
    s1 += __shfl_xor(s1, 32); s2 += __shfl_xor(s2, 32);
    if ((tid & 63) < 16) { atomicAdd(&sstat[d], s1); atomicAdd(&sstat[cD + d], s2); }
    __syncthreads();
    if (tid < 2 * cD) atomicAdd(&stats[tid], sstat[tid]);
  }
}

// ---------------- launch ----------------
extern "C" void kernel_launch(void* const* d_in, const int* in_sizes, int n_in,
                              void* d_out, int out_size, void* d_ws, size_t ws_size,
                              hipStream_t stream) {
  const float* x_low    = (const float*)d_in[0];
  const float* z_std    = (const float*)d_in[1];
  const float* land     = (const float*)d_in[2];
  const int*   l2h_src  = (const int*)d_in[3];
  const int*   l2h_dst  = (const int*)d_in[4];
  const int*   hh_src   = (const int*)d_in[5];
  const int*   hh_dst   = (const int*)d_in[6];
  const float* gWih     = (const float*)d_in[7];
  const float* gWhh     = (const float*)d_in[8];
  const float* gbih     = (const float*)d_in[9];
  const float* gbhh     = (const float*)d_in[10];
  const float* dW       = (const float*)d_in[11];
  const float* db       = (const float*)d_in[12];
  const float* bn_enc_g = (const float*)d_in[13];
  const float* bn_enc_b = (const float*)d_in[14];
  const float* Wrel     = (const float*)d_in[15];
  const float* brel     = (const float*)d_in[16];
  const float* Wroot    = (const float*)d_in[17];
  const float* gat_Wl   = (const float*)d_in[18];
  const float* gat_bl   = (const float*)d_in[19];
  const float* gat_Wr   = (const float*)d_in[20];
  const float* gat_br   = (const float*)d_in[21];
  const float* gat_att  = (const float*)d_in[22];
  const float* gat_bias = (const float*)d_in[23];
  const float* bn_g     = (const float*)d_in[24];
  const float* bn_b     = (const float*)d_in[25];
  const float* pred_W   = (const float*)d_in[26];
  const float* pred_b   = (const float*)d_in[27];

  float* ws = (float*)d_ws;
  float* hs   = ws + OFF_HS;
  float* agg  = ws + OFF_AGG;
  float* enc  = ws + OFF_ENC;
  float* xA   = ws + OFF_XA;
  float* xB   = ws + OFF_XB;
  float* xl   = ws + OFF_XL;
  float* xr   = ws + OFF_XR;
  float* statsEnc = ws + OFF_STAT;
  float* statsX   = ws + OFF_STAT + 64;
  int* rp_hh  = (int*)(ws + OFF_RPH);
  int* src_hh = (int*)(ws + OFF_SRH);
  int* rp_l2h = (int*)(ws + OFF_RPL);
  int* src_l2h= (int*)(ws + OFF_SRL);
  int* cursor = (int*)(ws + OFF_CUR);
  int* part   = (int*)(ws + OFF_PART);
  unsigned short* xlb = (unsigned short*)(ws + OFF_XLB);

  hipMemsetAsync(statsEnc, 0, 256 * sizeof(float), stream);

  // --- CSR build: hh ---
  hipMemsetAsync(cursor, 0, cN_HIGH * sizeof(int), stream);
  k_hist<<<(cE_HH + 255) / 256, 256, 0, stream>>>(hh_dst, cE_HH, cursor);
  k_scan_local<<<SC_NB, 256, 0, stream>>>(cursor, cN_HIGH, rp_hh, part);
  k_scan_top<<<1, 256, 0, stream>>>(part, SC_NB, rp_hh + cN_HIGH);
  k_scan_add<<<SC_NB, 256, 0, stream>>>(rp_hh, part, cN_HIGH, cursor);
  k_scatter<<<(cE_HH + 255) / 256, 256, 0, stream>>>(hh_src, hh_dst, cE_HH, cursor, src_hh);
  // --- CSR build: l2h ---
  hipMemsetAsync(cursor, 0, cN_HIGH * sizeof(int), stream);
  k_hist<<<(cE_L2H + 255) / 256, 256, 0, stream>>>(l2h_dst, cE_L2H, cursor);
  k_scan_local<<<SC_NB, 256, 0, stream>>>(cursor, cN_HIGH, rp_l2h, part);
  k_scan_top<<<1, 256, 0, stream>>>(part, SC_NB, rp_l2h + cN_HIGH);
  k_scan_add<<<SC_NB, 256, 0, stream>>>(rp_l2h, part, cN_HIGH, cursor);
  k_scatter<<<(cE_L2H + 255) / 256, 256, 0, stream>>>(l2h_src, l2h_dst, cE_L2H, cursor, src_l2h);

  // --- encoder ---
  k_gru<<<cN_LOW / GRU_NODES, GRU_BLOCK, 0, stream>>>(x_low, gWih, gWhh, gbih, gbhh, hs);
  k_dense<<<cN_LOW / 32, 256, 0, stream>>>(hs, dW, db, enc, statsEnc);
  k_gather_csr<<<cN_HIGH / 8, 256, 0, stream>>>(enc, rp_l2h, src_l2h, statsEnc,
                                                bn_enc_g, bn_enc_b, agg);
  const int NODE_GRID = (cN_HIGH + 255) / 256;
  k_down<<<NODE_GRID, 256, 0, stream>>>(agg, z_std, land, Wrel, brel, Wroot, xA, statsX);

  // --- 5 GATv2 layers ---
  for (int i = 0; i < cNL; ++i) {
    float* xin  = (i & 1) ? xB : xA;
    float* xout = (i & 1) ? xA : xB;
    k_transform<<<NODE_GRID, 256, 0, stream>>>(xin, statsX + 32 * i,
                                               bn_g + 16 * i, bn_b + 16 * i,
                                               gat_Wl + 256 * i, gat_bl + 16 * i,
                                               gat_Wr + 256 * i, gat_br + 16 * i,
                                               (i > 0) ? 1 : 0, xl, xr, xlb);
    if (i < cNL - 1) {
      k_edge<0><<<cN_HIGH / 16, 256, 0, stream>>>(xl, xr, xlb, rp_hh, src_hh,
                                                  gat_att + 16 * i, gat_bias + 16 * i,
                                                  nullptr, nullptr,
                                                  xout, statsX + 32 * (i + 1), nullptr);
    } else {
      k_edge<1><<<cN_HIGH / 16, 256, 0, stream>>>(xl, xr, xlb, rp_hh, src_hh,
                                                  gat_att + 16 * i, gat_bias + 16 * i,
                                                  pred_W, pred_b,
                                                  nullptr, nullptr, (float*)d_out);
    }
  }
}

// Round 9
// 1145.897 us; speedup vs baseline: 1.2879x; 1.2879x over previous
//
#include <hip/hip_runtime.h>
#include <hip/hip_bf16.h>
#include <cstddef>

// ---------------- problem constants ----------------
constexpr int cN_LOW  = 20000;
constexpr int cN_HIGH = 150000;
constexpr int cSEQ = 25;
constexpr int cHIN = 25;
constexpr int cHHID = 25;
constexpr int cENC = 32;
constexpr int cHIGH_IN = 7;
constexpr int cD = 16;
constexpr int cNL = 5;
constexpr int cE_L2H = 1350000;
constexpr int cE_HH = 1200000;
constexpr float cEPS = 1e-5f;
constexpr float cSLOPE = 0.2f;
constexpr float INV_NLOW  = 1.0f / (float)cN_LOW;
constexpr float INV_NHIGH = 1.0f / (float)cN_HIGH;

constexpr int cHSP = 628;     // padded hs row stride (16B-aligned rows)

// scan geometry
constexpr int SC_ELEM = 1024;
constexpr int SC_NB   = (cN_HIGH + SC_ELEM - 1) / SC_ELEM;     // 147
static_assert(SC_NB <= 256, "top scan assumes <=256 partials");

// ---------------- workspace layout (4-byte element offsets) ----------------
constexpr size_t OFF_HS   = 0;                                   // [N_LOW*628]
constexpr size_t SZ_HS    = (size_t)cN_LOW * cHSP;
constexpr size_t OFF_AGG  = 0;                                   // alias (hs dead after k_dense)
constexpr size_t OFF_ENC  = OFF_HS + SZ_HS;                      // [N_LOW*32]
constexpr size_t SZ_ENC   = (size_t)cN_LOW * cENC;
constexpr size_t OFF_XA   = OFF_ENC + SZ_ENC;
constexpr size_t OFF_XB   = OFF_XA + (size_t)cN_HIGH * cD;
constexpr size_t OFF_XL   = OFF_XB + (size_t)cN_HIGH * cD;
constexpr size_t OFF_XR   = OFF_XL + (size_t)cN_HIGH * cD;
constexpr size_t OFF_STAT = OFF_XR + (size_t)cN_HIGH * cD;       // [256]
constexpr size_t OFF_RPH  = OFF_STAT + 256;                      // rowptr_hh [N_HIGH+4]
constexpr size_t OFF_SRH  = OFF_RPH + cN_HIGH + 4;               // src_hh [E_HH]
constexpr size_t OFF_RPL  = OFF_SRH + cE_HH;                     // rowptr_l2h [N_HIGH+4]
constexpr size_t OFF_SRL  = OFF_RPL + cN_HIGH + 4;               // src_l2h [E_L2H]
constexpr size_t OFF_CUR  = OFF_SRL + cE_L2H;                    // cursor [N_HIGH]
constexpr size_t OFF_PART = OFF_CUR + cN_HIGH;                   // partials [256]
constexpr size_t OFF_XLB  = OFF_PART + 256;                      // xl bf16 [N_HIGH*16 ushort]

__device__ __forceinline__ float fast_sigmoid(float a) {
  return __builtin_amdgcn_rcpf(1.0f + __expf(-a));
}
__device__ __forceinline__ float fast_tanh(float a) {
  float t = __expf(-2.0f * a);
  return (1.0f - t) * __builtin_amdgcn_rcpf(1.0f + t);
}
__device__ __forceinline__ unsigned int f32_to_bf16_bits(float f) {
  unsigned int u = __float_as_uint(f);
  return (u + 0x7FFFu + ((u >> 16) & 1u)) >> 16;     // RNE
}

// ---------------- GRU kernel (gate-split) ----------------
// thread = (node, j, side): side 0 computes the 3 x-side partial dots with
// Wih rows in 75 VGPRs; side 1 the h-side with Whh rows. Partials meet in
// LDS; side-1 threads finalize. ~95 VGPR -> no spill (r7/r8: the 150-weight
// thread-per-(node,j) variant is stuck at the 128-VGPR cliff).
constexpr int GN = 5;                 // nodes per block
constexpr int GB = GN * 50;           // 250 threads

__global__ __launch_bounds__(256, 4)
void k_gru(const float* __restrict__ x_low,
           const float* __restrict__ Wih, const float* __restrict__ Whh,
           const float* __restrict__ bih, const float* __restrict__ bhh,
           float* __restrict__ hs) {
  __shared__ float sx[2][GN][25];
  __shared__ float sh[2][GN][25];
  __shared__ float sgi[GN][76];
  __shared__ float sgh[GN][76];

  int tid = threadIdx.x;
  int nl  = tid / 50;
  int rem = tid % 50;
  int s   = rem / 25;          // 0: x-side, 1: h-side
  int j   = rem % 25;
  int n   = blockIdx.x * GN + nl;

  const float* Wb = (s == 0) ? Wih : Whh;
  const float* bb = (s == 0) ? bih : bhh;
  float w0[25], w1[25], w2[25];
  #pragma unroll
  for (int i = 0; i < 25; ++i) {
    w0[i] = Wb[j * 25 + i];
    w1[i] = Wb[(25 + j) * 25 + i];
    w2[i] = Wb[(50 + j) * 25 + i];
  }
  float b0 = bb[j], b1 = bb[25 + j], b2 = bb[50 + j];

  const float* xrow = x_low + (size_t)n * 625;
  float* hrow = hs + (size_t)n * cHSP;
  if (s == 0 && j < 3) hrow[625 + j] = 0.0f;   // zero hs pad for dense float4 reads

  if (s == 0) { sh[0][nl][j] = 0.0f; sx[0][nl][j] = xrow[j]; }
  __syncthreads();

  int p = 0, q = 0;
  for (int t = 0; t < cSEQ; ++t) {
    if (s == 0 && t + 1 < cSEQ) sx[q ^ 1][nl][j] = xrow[(t + 1) * 25 + j];
    const float* vin = (s == 0) ? &sx[q][nl][0] : &sh[p][nl][0];
    float g0 = b0, g1 = b1, g2 = b2;
    #pragma unroll
    for (int i = 0; i < 25; ++i) {
      float v = vin[i];
      g0 += w0[i] * v;
      g1 += w1[i] * v;
      g2 += w2[i] * v;
    }
    float* gout = (s == 0) ? &sgi[nl][0] : &sgh[nl][0];
    gout[j] = g0; gout[25 + j] = g1; gout[50 + j] = g2;
    __syncthreads();
    if (s == 1) {
      float r  = fast_sigmoid(sgi[nl][j] + sgh[nl][j]);
      float z  = fast_sigmoid(sgi[nl][25 + j] + sgh[nl][25 + j]);
      float nn = fast_tanh(sgi[nl][50 + j] + r * sgh[nl][50 + j]);
      float hnew = (1.0f - z) * nn + z * sh[p][nl][j];
      sh[p ^ 1][nl][j] = hnew;
      hrow[t * 25 + j] = hnew;
    }
    p ^= 1; q ^= 1;
    __syncthreads();
  }
}

// ---------------- dense 625->32 + relu + BN stats ----------------
__global__ __launch_bounds__(256)
void k_dense(const float* __restrict__ hs, const float* __restrict__ W,
             const float* __restrict__ b, float* __restrict__ enc,
             float* __restrict__ statsEnc) {
  __shared__ __align__(16) float sW[cENC * cHSP];    // 80.4 KB
  __shared__ float sstat[2 * cENC];
  int tid = threadIdx.x;
  for (int i = tid; i < cENC * 625; i += 256) {
    int e2 = i / 625, f2 = i % 625;
    sW[e2 * cHSP + f2] = W[i];
  }
  if (tid < cENC * 3) { int e2 = tid / 3; sW[e2 * cHSP + 625 + tid % 3] = 0.0f; }
  if (tid < 2 * cENC) sstat[tid] = 0.0f;
  __syncthreads();

  int e  = tid & 31;
  int g  = tid >> 5;                    // 0..7
  int n0 = blockIdx.x * 32 + g * 4;
  const float4* H0 = (const float4*)(hs + (size_t)(n0 + 0) * cHSP);
  const float4* H1 = (const float4*)(hs + (size_t)(n0 + 1) * cHSP);
  const float4* H2 = (const float4*)(hs + (size_t)(n0 + 2) * cHSP);
  const float4* H3 = (const float4*)(hs + (size_t)(n0 + 3) * cHSP);
  const float4* W4 = (const float4*)(sW + (size_t)e * cHSP);
  float a0 = 0.0f, a1 = 0.0f, a2 = 0.0f, a3 = 0.0f;
  #pragma unroll 2
  for (int f = 0; f < cHSP / 4; ++f) {
    float4 w = W4[f];
    float4 h0 = H0[f], h1 = H1[f], h2 = H2[f], h3 = H3[f];
    a0 += w.x * h0.x + w.y * h0.y + w.z * h0.z + w.w * h0.w;
    a1 += w.x * h1.x + w.y * h1.y + w.z * h1.z + w.w * h1.w;
    a2 += w.x * h2.x + w.y * h2.y + w.z * h2.z + w.w * h2.w;
    a3 += w.x * h3.x + w.y * h3.y + w.z * h3.z + w.w * h3.w;
  }
  float bb = b[e];
  float v0 = fmaxf(a0 + bb, 0.0f);
  float v1 = fmaxf(a1 + bb, 0.0f);
  float v2 = fmaxf(a2 + bb, 0.0f);
  float v3 = fmaxf(a3 + bb, 0.0f);
  enc[(size_t)(n0 + 0) * cENC + e] = v0;
  enc[(size_t)(n0 + 1) * cENC + e] = v1;
  enc[(size_t)(n0 + 2) * cENC + e] = v2;
  enc[(size_t)(n0 + 3) * cENC + e] = v3;

  float p = v0 + v1 + v2 + v3;
  float q = v0 * v0 + v1 * v1 + v2 * v2 + v3 * v3;
  p += __shfl_down(p, 32);
  q += __shfl_down(q, 32);
  if ((tid & 63) < 32) { atomicAdd(&sstat[e], p); atomicAdd(&sstat[cENC + e], q); }
  __syncthreads();
  if (tid < 2 * cENC) atomicAdd(&statsEnc[tid], sstat[tid]);
}

// ---------------- CSR build ----------------
__global__ void k_hist(const int* __restrict__ dst, int nE, int* __restrict__ cnt) {
  int e = blockIdx.x * 256 + threadIdx.x;
  if (e < nE) atomicAdd(&cnt[dst[e]], 1);
}

__global__ void k_scan_local(const int* __restrict__ deg, int n,
                             int* __restrict__ out, int* __restrict__ partial) {
  int tid = threadIdx.x;
  int base = blockIdx.x * SC_ELEM + tid * 4;
  int4 v = make_int4(0, 0, 0, 0);
  if (base + 3 < n) v = *(const int4*)(deg + base);
  else { int* pv = (int*)&v; for (int k = 0; k < 4; ++k) if (base + k < n) pv[k] = deg[base + k]; }
  int tsum = v.x + v.y + v.z + v.w;
  int lane = tid & 63;
  int inc = tsum;
  #pragma unroll
  for (int o = 1; o < 64; o <<= 1) { int t = __shfl_up(inc, o); if (lane >= o) inc += t; }
  __shared__ int wtot[4];
  if (lane == 63) wtot[tid >> 6] = inc;
  __syncthreads();
  int w = tid >> 6, wbase = 0;
  #pragma unroll
  for (int k = 0; k < 3; ++k) if (k < w) wbase += wtot[k];
  int ebase = wbase + inc - tsum;
  int4 o4;
  o4.x = ebase; o4.y = ebase + v.x; o4.z = o4.y + v.y; o4.w = o4.z + v.z;
  if (base + 3 < n) *(int4*)(out + base) = o4;
  else { int* po = (int*)&o4; for (int k = 0; k < 4; ++k) if (base + k < n) out[base + k] = po[k]; }
  if (tid == 255) partial[blockIdx.x] = wbase + inc;
}

__global__ void k_scan_top(int* __restrict__ partial, int nb, int* __restrict__ total_out) {
  __shared__ int sd[256];
  int tid = threadIdx.x;
  int v = (tid < nb) ? partial[tid] : 0;
  sd[tid] = v;
  __syncthreads();
  for (int off = 1; off < 256; off <<= 1) {
    int t = (tid >= off) ? sd[tid - off] : 0;
    __syncthreads();
    sd[tid] += t;
    __syncthreads();
  }
  if (tid < nb) partial[tid] = sd[tid] - v;
  if (tid == 255) *total_out = sd[255];
}

__global__ void k_scan_add(int* __restrict__ rowptr, const int* __restrict__ partial,
                           int n, int* __restrict__ cursor) {
  int base = blockIdx.x * SC_ELEM + threadIdx.x * 4;
  int add = partial[blockIdx.x];
  if (base + 3 < n) {
    int4 v = *(int4*)(rowptr + base);
    v.x += add; v.y += add; v.z += add; v.w += add;
    *(int4*)(rowptr + base) = v;
    *(int4*)(cursor + base) = v;
  } else {
    for (int k = 0; k < 4; ++k)
      if (base + k < n) { int t = rowptr[base + k] + add; rowptr[base + k] = t; cursor[base + k] = t; }
  }
}

__global__ void k_scatter(const int* __restrict__ src, const int* __restrict__ dst, int nE,
                          int* __restrict__ cursor, int* __restrict__ out) {
  int e = blockIdx.x * 256 + threadIdx.x;
  if (e < nE) {
    int pos = atomicAdd(&cursor[dst[e]], 1);
    out[pos] = src[e];
  }
}

// ---------------- l2h gather via CSR ----------------
__global__ void k_gather_csr(const float* __restrict__ enc, const int* __restrict__ rowptr,
                             const int* __restrict__ srcs, const float* __restrict__ statsEnc,
                             const float* __restrict__ g, const float* __restrict__ bb,
                             float* __restrict__ agg) {
  __shared__ float ssc[cENC], ssh[cENC];
  int tid = threadIdx.x;
  if (tid < cENC) {
    float m = statsEnc[tid] * INV_NLOW;
    float var = statsEnc[cENC + tid] * INV_NLOW - m * m;
    float sc = g[tid] * rsqrtf(var + cEPS);
    ssc[tid] = sc;
    ssh[tid] = bb[tid] - m * sc;
  }
  __syncthreads();
  int c = tid & 31;
  int n = blockIdx.x * 8 + (tid >> 5);
  int lo = rowptr[n], hi = rowptr[n + 1];
  float sum = 0.0f;
  for (int i = lo; i < hi; ++i) {
    int s = srcs[i];
    sum += enc[(size_t)s * cENC + c];
  }
  float deg = (float)(hi - lo);
  agg[(size_t)n * cENC + c] = (ssc[c] * sum + deg * ssh[c]) / fmaxf(deg, 1.0f);
}

// ---------------- down-projection + BN0 stats ----------------
__global__ void k_down(const float* __restrict__ agg,
                       const float* __restrict__ z_std, const float* __restrict__ land,
                       const float* __restrict__ Wrel, const float* __restrict__ brel,
                       const float* __restrict__ Wroot,
                       float* __restrict__ x0, float* __restrict__ stats) {
  __shared__ float sstat[2 * cD];
  __shared__ float sWrel[cD * cENC], sWroot[cD * cHIGH_IN], sbrel[cD];
  int tid = threadIdx.x;
  if (tid < 2 * cD) sstat[tid] = 0.0f;
  for (int i = tid; i < cD * cENC; i += 256) sWrel[i] = Wrel[i];
  if (tid < cD * cHIGH_IN) sWroot[tid] = Wroot[tid];
  if (tid < cD) sbrel[tid] = brel[tid];
  __syncthreads();

  int n = blockIdx.x * 256 + tid;
  bool valid = n < cN_HIGH;
  float a[cENC], zz[cHIGH_IN];
  if (valid) {
    const float4* ar4 = (const float4*)(agg + (size_t)n * cENC);
    #pragma unroll
    for (int k = 0; k < cENC / 4; ++k) {
      float4 t4 = ar4[k];
      a[4*k] = t4.x; a[4*k+1] = t4.y; a[4*k+2] = t4.z; a[4*k+3] = t4.w;
    }
    #pragma unroll
    for (int k = 0; k < 6; ++k) zz[k] = z_std[(size_t)n * 6 + k];
    zz[6] = land[n];
  } else {
    #pragma unroll
    for (int k = 0; k < cENC; ++k) a[k] = 0.0f;
    #pragma unroll
    for (int k = 0; k < cHIGH_IN; ++k) zz[k] = 0.0f;
  }
  int lane = tid & 63;
  #pragma unroll
  for (int d = 0; d < cD; ++d) {
    float acc = sbrel[d];
    #pragma unroll
    for (int k = 0; k < cENC; ++k) acc += a[k] * sWrel[d * cENC + k];
    #pragma unroll
    for (int k = 0; k < cHIGH_IN; ++k) acc += zz[k] * sWroot[d * cHIGH_IN + k];
    if (valid) x0[(size_t)n * cD + d] = acc;
    float v = valid ? acc : 0.0f;
    float s1 = v, s2 = v * v;
    #pragma unroll
    for (int o = 32; o > 0; o >>= 1) { s1 += __shfl_down(s1, o); s2 += __shfl_down(s2, o); }
    if (lane == 0) { atomicAdd(&sstat[d], s1); atomicAdd(&sstat[cD + d], s2); }
  }
  __syncthreads();
  if (tid < 2 * cD) atomicAdd(&stats[tid], sstat[tid]);
}

// ---------------- GAT node transform (also emits bf16 xl rows) ----------------
__global__ void k_transform(const float* __restrict__ xin, const float* __restrict__ stats,
                            const float* __restrict__ g, const float* __restrict__ b,
                            const float* __restrict__ Wl, const float* __restrict__ bl,
                            const float* __restrict__ Wr, const float* __restrict__ br,
                            int applyRelu,
                            float* __restrict__ xl, float* __restrict__ xr,
                            unsigned short* __restrict__ xlb) {
  __shared__ float ssc[cD], ssh[cD], sWl[cD * cD], sWr[cD * cD], sbl[cD], sbr[cD];
  int tid = threadIdx.x;
  if (tid < cD) {
    float m = stats[tid] * INV_NHIGH;
    float v = stats[cD + tid] * INV_NHIGH - m * m;
    float sc = g[tid] * rsqrtf(v + cEPS);
    ssc[tid] = sc;
    ssh[tid] = b[tid] - m * sc;
    sbl[tid] = bl[tid];
    sbr[tid] = br[tid];
  }
  if (tid < cD * cD) { sWl[tid] = Wl[tid]; sWr[tid] = Wr[tid]; }
  __syncthreads();

  int n = blockIdx.x * 256 + tid;
  if (n >= cN_HIGH) return;
  float act[cD];
  const float* xp = xin + (size_t)n * cD;
  #pragma unroll
  for (int d = 0; d < cD; ++d) {
    float v = xp[d] * ssc[d] + ssh[d];
    if (applyRelu) v = fmaxf(v, 0.0f);
    act[d] = v;
  }
  float alv[cD];
  float* xlp = xl + (size_t)n * cD;
  float* xrp = xr + (size_t)n * cD;
  #pragma unroll
  for (int d = 0; d < cD; ++d) {
    float al = sbl[d], ar = sbr[d];
    #pragma unroll
    for (int k = 0; k < cD; ++k) { al += act[k] * sWl[d * cD + k]; ar += act[k] * sWr[d * cD + k]; }
    alv[d] = al;
    xlp[d] = al;
    xrp[d] = ar;
  }
  uint4 w0, w1;
  unsigned int* pw = (unsigned int*)&w0;
  #pragma unroll
  for (int k = 0; k < 4; ++k)
    pw[k] = f32_to_bf16_bits(alv[2 * k]) | (f32_to_bf16_bits(alv[2 * k + 1]) << 16);
  unsigned int* pw1 = (unsigned int*)&w1;
  #pragma unroll
  for (int k = 0; k < 4; ++k)
    pw1[k] = f32_to_bf16_bits(alv[8 + 2 * k]) | (f32_to_bf16_bits(alv[8 + 2 * k + 1]) << 16);
  uint4* dst = (uint4*)(xlb + (size_t)n * cD);
  dst[0] = w0;
  dst[1] = w1;
}

// ---------------- fused GAT edge pass: 8 lanes/node, 2 ch/lane ----------------
// One packed-bf16 dword load per edge per lane (32B/row coalesced per group),
// 3-step shfl chain (was 4), 8 nodes per wave (was 4).
template<int FINAL>
__global__ __launch_bounds__(256)
void k_edge(const float* __restrict__ xl, const float* __restrict__ xr,
            const unsigned short* __restrict__ xlb,
            const int* __restrict__ rowptr, const int* __restrict__ srcs,
            const float* __restrict__ att, const float* __restrict__ bias,
            const float* __restrict__ pW, const float* __restrict__ pb,
            float* __restrict__ xout, float* __restrict__ stats,
            float* __restrict__ out) {
  __shared__ float satt[cD], sbias[cD], spw[cD];
  __shared__ float sstat[2 * cD];
  int tid = threadIdx.x;
  if (tid < cD) { satt[tid] = att[tid]; sbias[tid] = bias[tid]; spw[tid] = FINAL ? pW[tid] : 0.0f; }
  if (!FINAL && tid < 2 * cD) sstat[tid] = 0.0f;
  __syncthreads();

  int d2  = tid & 7;            // channel-pair index (channels 2*d2, 2*d2+1)
  int grp = tid >> 3;           // node within block, 0..31
  int n   = blockIdx.x * 32 + grp;
  bool valid = n < cN_HIGH;

  float a0 = satt[2 * d2], a1 = satt[2 * d2 + 1];
  float xr0 = 0.0f, xr1 = 0.0f, xs0 = 0.0f, xs1 = 0.0f;
  int lo = 0, hi = 0;
  if (valid) {
    float2 t2 = *(const float2*)(xr + (size_t)n * cD + 2 * d2);
    xr0 = t2.x; xr1 = t2.y;
    float2 t3 = *(const float2*)(xl + (size_t)n * cD + 2 * d2);
    xs0 = t3.x; xs1 = t3.y;
    lo = rowptr[n]; hi = rowptr[n + 1];
  }

  // self loop
  float w0 = xs0 + xr0; w0 = w0 > 0.0f ? w0 : cSLOPE * w0;
  float w1 = xs1 + xr1; w1 = w1 > 0.0f ? w1 : cSLOPE * w1;
  float pq = w0 * a0 + w1 * a1;
  pq += __shfl_xor(pq, 1); pq += __shfl_xor(pq, 2); pq += __shfl_xor(pq, 4);
  float ex = __expf(pq);
  float denom = ex;
  float num0 = ex * xs0, num1 = ex * xs1;

  const unsigned int* xlw = (const unsigned int*)xlb;
  int i = lo;
  for (; i + 3 < hi; i += 4) {
    int s0 = srcs[i], s1 = srcs[i + 1], s2 = srcs[i + 2], s3 = srcs[i + 3];
    unsigned int v0 = xlw[(size_t)s0 * 8 + d2];
    unsigned int v1 = xlw[(size_t)s1 * 8 + d2];
    unsigned int v2 = xlw[(size_t)s2 * 8 + d2];
    unsigned int v3 = xlw[(size_t)s3 * 8 + d2];
    float x00 = __uint_as_float(v0 << 16), x01 = __uint_as_float(v0 & 0xFFFF0000u);
    float x10 = __uint_as_float(v1 << 16), x11 = __uint_as_float(v1 & 0xFFFF0000u);
    float x20 = __uint_as_float(v2 << 16), x21 = __uint_as_float(v2 & 0xFFFF0000u);
    float x30 = __uint_as_float(v3 << 16), x31 = __uint_as_float(v3 & 0xFFFF0000u);
    float u00 = x00 + xr0; u00 = u00 > 0.0f ? u00 : cSLOPE * u00;
    float u01 = x01 + xr1; u01 = u01 > 0.0f ? u01 : cSLOPE * u01;
    float u10 = x10 + xr0; u10 = u10 > 0.0f ? u10 : cSLOPE * u10;
    float u11 = x11 + xr1; u11 = u11 > 0.0f ? u11 : cSLOPE * u11;
    float u20 = x20 + xr0; u20 = u20 > 0.0f ? u20 : cSLOPE * u20;
    float u21 = x21 + xr1; u21 = u21 > 0.0f ? u21 : cSLOPE * u21;
    float u30 = x30 + xr0; u30 = u30 > 0.0f ? u30 : cSLOPE * u30;
    float u31 = x31 + xr1; u31 = u31 > 0.0f ? u31 : cSLOPE * u31;
    float q0 = u00 * a0 + u01 * a1;
    float q1 = u10 * a0 + u11 * a1;
    float q2 = u20 * a0 + u21 * a1;
    float q3 = u30 * a0 + u31 * a1;
    q0 += __shfl_xor(q0, 1); q1 += __shfl_xor(q1, 1); q2 += __shfl_xor(q2, 1); q3 += __shfl_xor(q3, 1);
    q0 += __shfl_xor(q0, 2); q1 += __shfl_xor(q1, 2); q2 += __shfl_xor(q2, 2); q3 += __shfl_xor(q3, 2);
    q0 += __shfl_xor(q0, 4); q1 += __shfl_xor(q1, 4); q2 += __shfl_xor(q2, 4); q3 += __shfl_xor(q3, 4);
    float e0 = __expf(q0), e1 = __expf(q1), e2c = __expf(q2), e3 = __expf(q3);
    denom += (e0 + e1) + (e2c + e3);
    num0 += e0 * x00 + e1 * x10 + e2c * x20 + e3 * x30;
    num1 += e0 * x01 + e1 * x11 + e2c * x21 + e3 * x31;
  }
  for (; i < hi; ++i) {
    int s = srcs[i];
    unsigned int v = xlw[(size_t)s * 8 + d2];
    float x0 = __uint_as_float(v << 16), x1 = __uint_as_float(v & 0xFFFF0000u);
    float u0 = x0 + xr0; u0 = u0 > 0.0f ? u0 : cSLOPE * u0;
    float u1 = x1 + xr1; u1 = u1 > 0.0f ? u1 : cSLOPE * u1;
    float q = u0 * a0 + u1 * a1;
    q += __shfl_xor(q, 1); q += __shfl_xor(q, 2); q += __shfl_xor(q, 4);
    float e = __expf(q);
    denom += e;
    num0 += e * x0;
    num1 += e * x1;
  }
  float cnt = (float)(hi - lo + 1);
  float inv = __builtin_amdgcn_rcpf(denom * cnt);
  float res0 = num0 * inv + sbias[2 * d2];
  float res1 = num1 * inv + sbias[2 * d2 + 1];

  if (FINAL) {
    float t = fmaxf(res0, 0.0f) * spw[2 * d2] + fmaxf(res1, 0.0f) * spw[2 * d2 + 1];
    t += __shfl_xor(t, 1); t += __shfl_xor(t, 2); t += __shfl_xor(t, 4);
    if (valid && d2 == 0) out[n] = t + pb[0];
  } else {
    if (!valid) { res0 = 0.0f; res1 = 0.0f; }
    else *(float2*)(xout + (size_t)n * cD + 2 * d2) = make_float2(res0, res1);
    float s10 = res0, s11 = res1, s20 = res0 * res0, s21 = res1 * res1;
    s10 += __shfl_xor(s10, 8);  s11 += __shfl_xor(s11, 8);  s20 += __shfl_xor(s20, 8);  s21 += __shfl_xor(s21, 8);
    s10 += __shfl_xor(s10, 16); s11 += __shfl_xor(s11, 16); s20 += __shfl_xor(s20, 16); s21 += __shfl_xor(s21, 16);
    s10 += __shfl_xor(s10, 32); s11 += __shfl_xor(s11, 32); s20 += __shfl_xor(s20, 32); s21 += __shfl_xor(s21, 32);
    if ((tid & 63) < 8) {
      atomicAdd(&sstat[2 * d2], s10);
      atomicAdd(&sstat[2 * d2 + 1], s11);
      atomicAdd(&sstat[cD + 2 * d2], s20);
      atomicAdd(&sstat[cD + 2 * d2 + 1], s21);
    }
    __syncthreads();
    if (tid < 2 * cD) atomicAdd(&stats[tid], sstat[tid]);
  }
}

// ---------------- launch ----------------
extern "C" void kernel_launch(void* const* d_in, const int* in_sizes, int n_in,
                              void* d_out, int out_size, void* d_ws, size_t ws_size,
                              hipStream_t stream) {
  const float* x_low    = (const float*)d_in[0];
  const float* z_std    = (const float*)d_in[1];
  const float* land     = (const float*)d_in[2];
  const int*   l2h_src  = (const int*)d_in[3];
  const int*   l2h_dst  = (const int*)d_in[4];
  const int*   hh_src   = (const int*)d_in[5];
  const int*   hh_dst   = (const int*)d_in[6];
  const float* gWih     = (const float*)d_in[7];
  const float* gWhh     = (const float*)d_in[8];
  const float* gbih     = (const float*)d_in[9];
  const float* gbhh     = (const float*)d_in[10];
  const float* dW       = (const float*)d_in[11];
  const float* db       = (const float*)d_in[12];
  const float* bn_enc_g = (const float*)d_in[13];
  const float* bn_enc_b = (const float*)d_in[14];
  const float* Wrel     = (const float*)d_in[15];
  const float* brel     = (const float*)d_in[16];
  const float* Wroot    = (const float*)d_in[17];
  const float* gat_Wl   = (const float*)d_in[18];
  const float* gat_bl   = (const float*)d_in[19];
  const float* gat_Wr   = (const float*)d_in[20];
  const float* gat_br   = (const float*)d_in[21];
  const float* gat_att  = (const float*)d_in[22];
  const float* gat_bias = (const float*)d_in[23];
  const float* bn_g     = (const float*)d_in[24];
  const float* bn_b     = (const float*)d_in[25];
  const float* pred_W   = (const float*)d_in[26];
  const float* pred_b   = (const float*)d_in[27];

  float* ws = (float*)d_ws;
  float* hs   = ws + OFF_HS;
  float* agg  = ws + OFF_AGG;
  float* enc  = ws + OFF_ENC;
  float* xA   = ws + OFF_XA;
  float* xB   = ws + OFF_XB;
  float* xl   = ws + OFF_XL;
  float* xr   = ws + OFF_XR;
  float* statsEnc = ws + OFF_STAT;
  float* statsX   = ws + OFF_STAT + 64;
  int* rp_hh  = (int*)(ws + OFF_RPH);
  int* src_hh = (int*)(ws + OFF_SRH);
  int* rp_l2h = (int*)(ws + OFF_RPL);
  int* src_l2h= (int*)(ws + OFF_SRL);
  int* cursor = (int*)(ws + OFF_CUR);
  int* part   = (int*)(ws + OFF_PART);
  unsigned short* xlb = (unsigned short*)(ws + OFF_XLB);

  hipMemsetAsync(statsEnc, 0, 256 * sizeof(float), stream);

  // --- CSR build: hh ---
  hipMemsetAsync(cursor, 0, cN_HIGH * sizeof(int), stream);
  k_hist<<<(cE_HH + 255) / 256, 256, 0, stream>>>(hh_dst, cE_HH, cursor);
  k_scan_local<<<SC_NB, 256, 0, stream>>>(cursor, cN_HIGH, rp_hh, part);
  k_scan_top<<<1, 256, 0, stream>>>(part, SC_NB, rp_hh + cN_HIGH);
  k_scan_add<<<SC_NB, 256, 0, stream>>>(rp_hh, part, cN_HIGH, cursor);
  k_scatter<<<(cE_HH + 255) / 256, 256, 0, stream>>>(hh_src, hh_dst, cE_HH, cursor, src_hh);
  // --- CSR build: l2h ---
  hipMemsetAsync(cursor, 0, cN_HIGH * sizeof(int), stream);
  k_hist<<<(cE_L2H + 255) / 256, 256, 0, stream>>>(l2h_dst, cE_L2H, cursor);
  k_scan_local<<<SC_NB, 256, 0, stream>>>(cursor, cN_HIGH, rp_l2h, part);
  k_scan_top<<<1, 256, 0, stream>>>(part, SC_NB, rp_l2h + cN_HIGH);
  k_scan_add<<<SC_NB, 256, 0, stream>>>(rp_l2h, part, cN_HIGH, cursor);
  k_scatter<<<(cE_L2H + 255) / 256, 256, 0, stream>>>(l2h_src, l2h_dst, cE_L2H, cursor, src_l2h);

  // --- encoder ---
  k_gru<<<cN_LOW / GN, GB, 0, stream>>>(x_low, gWih, gWhh, gbih, gbhh, hs);
  k_dense<<<cN_LOW / 32, 256, 0, stream>>>(hs, dW, db, enc, statsEnc);
  k_gather_csr<<<cN_HIGH / 8, 256, 0, stream>>>(enc, rp_l2h, src_l2h, statsEnc,
                                                bn_enc_g, bn_enc_b, agg);
  const int NODE_GRID = (cN_HIGH + 255) / 256;
  k_down<<<NODE_GRID, 256, 0, stream>>>(agg, z_std, land, Wrel, brel, Wroot, xA, statsX);

  const int EDGE_GRID = (cN_HIGH + 31) / 32;
  // --- 5 GATv2 layers ---
  for (int i = 0; i < cNL; ++i) {
    float* xin  = (i & 1) ? xB : xA;
    float* xout = (i & 1) ? xA : xB;
    k_transform<<<NODE_GRID, 256, 0, stream>>>(xin, statsX + 32 * i,
                                               bn_g + 16 * i, bn_b + 16 * i,
                                               gat_Wl + 256 * i, gat_bl + 16 * i,
                                               gat_Wr + 256 * i, gat_br + 16 * i,
                                               (i > 0) ? 1 : 0, xl, xr, xlb);
    if (i < cNL - 1) {
      k_edge<0><<<EDGE_GRID, 256, 0, stream>>>(xl, xr, xlb, rp_hh, src_hh,
                                               gat_att + 16 * i, gat_bias + 16 * i,
                                               nullptr, nullptr,
                                               xout, statsX + 32 * (i + 1), nullptr);
    } else {
      k_edge<1><<<EDGE_GRID, 256, 0, stream>>>(xl, xr, xlb, rp_hh, src_hh,
                                               gat_att + 16 * i, gat_bias + 16 * i,
                                               pred_W, pred_b,
                                               nullptr, nullptr, (float*)d_out);
    }
  }
}

// Round 10
// 1082.539 us; speedup vs baseline: 1.3633x; 1.0585x over previous
//
#include <hip/hip_runtime.h>
#include <hip/hip_bf16.h>
#include <cstddef>

// ---------------- problem constants ----------------
constexpr int cN_LOW  = 20000;
constexpr int cN_HIGH = 150000;
constexpr int cSEQ = 25;
constexpr int cHIN = 25;
constexpr int cHHID = 25;
constexpr int cENC = 32;
constexpr int cHIGH_IN = 7;
constexpr int cD = 16;
constexpr int cNL = 5;
constexpr int cE_L2H = 1350000;
constexpr int cE_HH = 1200000;
constexpr float cEPS = 1e-5f;
constexpr float cSLOPE = 0.2f;
constexpr float INV_NLOW  = 1.0f / (float)cN_LOW;
constexpr float INV_NHIGH = 1.0f / (float)cN_HIGH;

constexpr int cHSP = 640;     // padded hs row stride: 10 exact 64-f chunks, 16B-aligned

// scan geometry
constexpr int SC_ELEM = 1024;
constexpr int SC_NB   = (cN_HIGH + SC_ELEM - 1) / SC_ELEM;     // 147
static_assert(SC_NB <= 256, "top scan assumes <=256 partials");

// ---------------- workspace layout (4-byte element offsets) ----------------
constexpr size_t OFF_HS   = 0;                                   // [N_LOW*640]
constexpr size_t SZ_HS    = (size_t)cN_LOW * cHSP;
constexpr size_t OFF_AGG  = 0;                                   // alias (hs dead after k_dense)
constexpr size_t OFF_ENC  = OFF_HS + SZ_HS;                      // [N_LOW*32]
constexpr size_t SZ_ENC   = (size_t)cN_LOW * cENC;
constexpr size_t OFF_XA   = OFF_ENC + SZ_ENC;
constexpr size_t OFF_XB   = OFF_XA + (size_t)cN_HIGH * cD;
constexpr size_t OFF_XL   = OFF_XB + (size_t)cN_HIGH * cD;
constexpr size_t OFF_XR   = OFF_XL + (size_t)cN_HIGH * cD;
constexpr size_t OFF_STAT = OFF_XR + (size_t)cN_HIGH * cD;       // [256]
constexpr size_t OFF_RPH  = OFF_STAT + 256;                      // rowptr_hh [N_HIGH+4]
constexpr size_t OFF_SRH  = OFF_RPH + cN_HIGH + 4;               // src_hh [E_HH]
constexpr size_t OFF_RPL  = OFF_SRH + cE_HH;                     // rowptr_l2h [N_HIGH+4]
constexpr size_t OFF_SRL  = OFF_RPL + cN_HIGH + 4;               // src_l2h [E_L2H]
constexpr size_t OFF_CUR  = OFF_SRL + cE_L2H;                    // cursor [N_HIGH]
constexpr size_t OFF_PART = OFF_CUR + cN_HIGH;                   // partials [256]
constexpr size_t OFF_XLB  = OFF_PART + 256;                      // xl bf16 [N_HIGH*16 ushort]

__device__ __forceinline__ float fast_sigmoid(float a) {
  return __builtin_amdgcn_rcpf(1.0f + __expf(-a));
}
__device__ __forceinline__ float fast_tanh(float a) {
  float t = __expf(-2.0f * a);
  return (1.0f - t) * __builtin_amdgcn_rcpf(1.0f + t);
}
__device__ __forceinline__ unsigned int f32_to_bf16_bits(float f) {
  unsigned int u = __float_as_uint(f);
  return (u + 0x7FFFu + ((u >> 16) & 1u)) >> 16;     // RNE
}

// ---------------- GRU kernel (gate-split) ----------------
constexpr int GN = 5;                 // nodes per block
constexpr int GB = GN * 50;           // 250 threads

__global__ __launch_bounds__(256, 4)
void k_gru(const float* __restrict__ x_low,
           const float* __restrict__ Wih, const float* __restrict__ Whh,
           const float* __restrict__ bih, const float* __restrict__ bhh,
           float* __restrict__ hs) {
  __shared__ float sx[2][GN][25];
  __shared__ float sh[2][GN][25];
  __shared__ float sgi[GN][76];
  __shared__ float sgh[GN][76];

  int tid = threadIdx.x;
  int nl  = tid / 50;
  int rem = tid % 50;
  int s   = rem / 25;          // 0: x-side, 1: h-side
  int j   = rem % 25;
  int n   = blockIdx.x * GN + nl;

  const float* Wb = (s == 0) ? Wih : Whh;
  const float* bb = (s == 0) ? bih : bhh;
  float w0[25], w1[25], w2[25];
  #pragma unroll
  for (int i = 0; i < 25; ++i) {
    w0[i] = Wb[j * 25 + i];
    w1[i] = Wb[(25 + j) * 25 + i];
    w2[i] = Wb[(50 + j) * 25 + i];
  }
  float b0 = bb[j], b1 = bb[25 + j], b2 = bb[50 + j];

  const float* xrow = x_low + (size_t)n * 625;
  float* hrow = hs + (size_t)n * cHSP;
  if (s == 0 && j < 15) hrow[625 + j] = 0.0f;   // zero hs pad (f 625..639) for dense chunks

  if (s == 0) { sh[0][nl][j] = 0.0f; sx[0][nl][j] = xrow[j]; }
  __syncthreads();

  int p = 0, q = 0;
  for (int t = 0; t < cSEQ; ++t) {
    if (s == 0 && t + 1 < cSEQ) sx[q ^ 1][nl][j] = xrow[(t + 1) * 25 + j];
    const float* vin = (s == 0) ? &sx[q][nl][0] : &sh[p][nl][0];
    float g0 = b0, g1 = b1, g2 = b2;
    #pragma unroll
    for (int i = 0; i < 25; ++i) {
      float v = vin[i];
      g0 += w0[i] * v;
      g1 += w1[i] * v;
      g2 += w2[i] * v;
    }
    float* gout = (s == 0) ? &sgi[nl][0] : &sgh[nl][0];
    gout[j] = g0; gout[25 + j] = g1; gout[50 + j] = g2;
    __syncthreads();
    if (s == 1) {
      float r  = fast_sigmoid(sgi[nl][j] + sgh[nl][j]);
      float z  = fast_sigmoid(sgi[nl][25 + j] + sgh[nl][25 + j]);
      float nn = fast_tanh(sgi[nl][50 + j] + r * sgh[nl][50 + j]);
      float hnew = (1.0f - z) * nn + z * sh[p][nl][j];
      sh[p ^ 1][nl][j] = hnew;
      hrow[t * 25 + j] = hnew;
    }
    p ^= 1; q ^= 1;
    __syncthreads();
  }
}

// ---------------- dense 625->32 + relu + BN stats (v4) ----------------
// lane = (channel-pair e2, node-group): 2 ch x 2 nodes = 4 acc.
// hs staged to LDS in 64-f chunks (coalesced float4, double-buffered, row
// stride 68 => the wave's 8 row addresses hit banks {0,4,..28}: conflict-free).
// W as transposed float2-pairs sW2[f][e2] => b64 reads covering all 32 banks.
// r9 version was broadcast-global-load latency-bound at 131us / 4 waves.
constexpr int cDN = 32;      // nodes per block
__global__ __launch_bounds__(256)
void k_dense(const float* __restrict__ hs, const float* __restrict__ W,
             const float* __restrict__ b, float* __restrict__ enc,
             float* __restrict__ statsEnc) {
  __shared__ __align__(16) float sW2[640 * 32];        // 80 KB: [f][e2-pair]
  __shared__ __align__(16) float sH[2][cDN * 68];      // 17.4 KB
  __shared__ float sstat[2 * cENC];
  int tid = threadIdx.x;
  for (int i = tid; i < 32 * 625; i += 256) {
    int e = i / 625, f = i % 625;
    sW2[f * 32 + (e & 15) * 2 + (e >> 4)] = W[i];      // coalesced read; LDS write conflicts once/block
  }
  for (int i = tid; i < 32 * 15; i += 256)
    sW2[(625 + (i >> 5)) * 32 + (i & 31)] = 0.0f;      // zero pad f=625..639 (avoid NaN garbage)
  if (tid < 2 * cENC) sstat[tid] = 0.0f;

  int e2 = tid & 15;
  int ng = (tid >> 4) & 3;
  int w  = tid >> 6;
  int rA = 8 * w + 2 * ng;
  int rB = rA + 1;
  size_t nbase = (size_t)blockIdx.x * cDN;

  int srow = tid >> 4;          // 0..15 (staging row)
  int sf4  = (tid & 15) * 4;    // float col within chunk
  const float* hsb = hs + nbase * cHSP;
  {
    float4 v0 = *(const float4*)(hsb + (size_t)srow * cHSP + sf4);
    float4 v1 = *(const float4*)(hsb + (size_t)(srow + 16) * cHSP + sf4);
    *(float4*)&sH[0][srow * 68 + sf4] = v0;
    *(float4*)&sH[0][(srow + 16) * 68 + sf4] = v1;
  }
  __syncthreads();

  float a00 = 0.0f, a01 = 0.0f, a10 = 0.0f, a11 = 0.0f;
  for (int c = 0; c < 10; ++c) {
    int buf = c & 1;
    if (c + 1 < 10) {
      const float* src = hsb + (c + 1) * 64;
      float4 v0 = *(const float4*)(src + (size_t)srow * cHSP + sf4);
      float4 v1 = *(const float4*)(src + (size_t)(srow + 16) * cHSP + sf4);
      *(float4*)&sH[buf ^ 1][srow * 68 + sf4] = v0;
      *(float4*)&sH[buf ^ 1][(srow + 16) * 68 + sf4] = v1;
    }
    const float* WC = sW2 + c * 64 * 32;
    #pragma unroll
    for (int fg = 0; fg < 16; ++fg) {
      float4 hA = *(const float4*)&sH[buf][rA * 68 + fg * 4];
      float4 hB = *(const float4*)&sH[buf][rB * 68 + fg * 4];
      const float* ha = (const float*)&hA;
      const float* hb = (const float*)&hB;
      #pragma unroll
      for (int k = 0; k < 4; ++k) {
        float2 wv = *(const float2*)&WC[(fg * 4 + k) * 32 + e2 * 2];
        a00 += wv.x * ha[k]; a01 += wv.y * ha[k];
        a10 += wv.x * hb[k]; a11 += wv.y * hb[k];
      }
    }
    __syncthreads();
  }
  float blo = b[e2], bhi = b[e2 + 16];
  float v00 = fmaxf(a00 + blo, 0.0f);
  float v01 = fmaxf(a01 + bhi, 0.0f);
  float v10 = fmaxf(a10 + blo, 0.0f);
  float v11 = fmaxf(a11 + bhi, 0.0f);
  size_t nA = nbase + rA, nB = nbase + rB;
  enc[nA * cENC + e2]      = v00;
  enc[nA * cENC + e2 + 16] = v01;
  enc[nB * cENC + e2]      = v10;
  enc[nB * cENC + e2 + 16] = v11;

  float s1lo = v00 + v10, s1hi = v01 + v11;
  float s2lo = v00 * v00 + v10 * v10, s2hi = v01 * v01 + v11 * v11;
  s1lo += __shfl_xor(s1lo, 16); s1hi += __shfl_xor(s1hi, 16);
  s2lo += __shfl_xor(s2lo, 16); s2hi += __shfl_xor(s2hi, 16);
  s1lo += __shfl_xor(s1lo, 32); s1hi += __shfl_xor(s1hi, 32);
  s2lo += __shfl_xor(s2lo, 32); s2hi += __shfl_xor(s2hi, 32);
  if ((tid & 63) < 16) {
    atomicAdd(&sstat[e2], s1lo);
    atomicAdd(&sstat[e2 + 16], s1hi);
    atomicAdd(&sstat[cENC + e2], s2lo);
    atomicAdd(&sstat[cENC + e2 + 16], s2hi);
  }
  __syncthreads();
  if (tid < 2 * cENC) atomicAdd(&statsEnc[tid], sstat[tid]);
}

// ---------------- CSR build ----------------
__global__ void k_hist(const int* __restrict__ dst, int nE, int* __restrict__ cnt) {
  int e = blockIdx.x * 256 + threadIdx.x;
  if (e < nE) atomicAdd(&cnt[dst[e]], 1);
}

__global__ void k_scan_local(const int* __restrict__ deg, int n,
                             int* __restrict__ out, int* __restrict__ partial) {
  int tid = threadIdx.x;
  int base = blockIdx.x * SC_ELEM + tid * 4;
  int4 v = make_int4(0, 0, 0, 0);
  if (base + 3 < n) v = *(const int4*)(deg + base);
  else { int* pv = (int*)&v; for (int k = 0; k < 4; ++k) if (base + k < n) pv[k] = deg[base + k]; }
  int tsum = v.x + v.y + v.z + v.w;
  int lane = tid & 63;
  int inc = tsum;
  #pragma unroll
  for (int o = 1; o < 64; o <<= 1) { int t = __shfl_up(inc, o); if (lane >= o) inc += t; }
  __shared__ int wtot[4];
  if (lane == 63) wtot[tid >> 6] = inc;
  __syncthreads();
  int w = tid >> 6, wbase = 0;
  #pragma unroll
  for (int k = 0; k < 3; ++k) if (k < w) wbase += wtot[k];
  int ebase = wbase + inc - tsum;
  int4 o4;
  o4.x = ebase; o4.y = ebase + v.x; o4.z = o4.y + v.y; o4.w = o4.z + v.z;
  if (base + 3 < n) *(int4*)(out + base) = o4;
  else { int* po = (int*)&o4; for (int k = 0; k < 4; ++k) if (base + k < n) out[base + k] = po[k]; }
  if (tid == 255) partial[blockIdx.x] = wbase + inc;
}

__global__ void k_scan_top(int* __restrict__ partial, int nb, int* __restrict__ total_out) {
  __shared__ int sd[256];
  int tid = threadIdx.x;
  int v = (tid < nb) ? partial[tid] : 0;
  sd[tid] = v;
  __syncthreads();
  for (int off = 1; off < 256; off <<= 1) {
    int t = (tid >= off) ? sd[tid - off] : 0;
    __syncthreads();
    sd[tid] += t;
    __syncthreads();
  }
  if (tid < nb) partial[tid] = sd[tid] - v;
  if (tid == 255) *total_out = sd[255];
}

__global__ void k_scan_add(int* __restrict__ rowptr, const int* __restrict__ partial,
                           int n, int* __restrict__ cursor) {
  int base = blockIdx.x * SC_ELEM + threadIdx.x * 4;
  int add = partial[blockIdx.x];
  if (base + 3 < n) {
    int4 v = *(int4*)(rowptr + base);
    v.x += add; v.y += add; v.z += add; v.w += add;
    *(int4*)(rowptr + base) = v;
    *(int4*)(cursor + base) = v;
  } else {
    for (int k = 0; k < 4; ++k)
      if (base + k < n) { int t = rowptr[base + k] + add; rowptr[base + k] = t; cursor[base + k] = t; }
  }
}

__global__ void k_scatter(const int* __restrict__ src, const int* __restrict__ dst, int nE,
                          int* __restrict__ cursor, int* __restrict__ out) {
  int e = blockIdx.x * 256 + threadIdx.x;
  if (e < nE) {
    int pos = atomicAdd(&cursor[dst[e]], 1);
    out[pos] = src[e];
  }
}

// ---------------- l2h gather via CSR (2-way unrolled) ----------------
__global__ void k_gather_csr(const float* __restrict__ enc, const int* __restrict__ rowptr,
                             const int* __restrict__ srcs, const float* __restrict__ statsEnc,
                             const float* __restrict__ g, const float* __restrict__ bb,
                             float* __restrict__ agg) {
  __shared__ float ssc[cENC], ssh[cENC];
  int tid = threadIdx.x;
  if (tid < cENC) {
    float m = statsEnc[tid] * INV_NLOW;
    float var = statsEnc[cENC + tid] * INV_NLOW - m * m;
    float sc = g[tid] * rsqrtf(var + cEPS);
    ssc[tid] = sc;
    ssh[tid] = bb[tid] - m * sc;
  }
  __syncthreads();
  int c = tid & 31;
  int n = blockIdx.x * 8 + (tid >> 5);
  int lo = rowptr[n], hi = rowptr[n + 1];
  float sum = 0.0f;
  int i = lo;
  for (; i + 1 < hi; i += 2) {
    int s0 = srcs[i], s1 = srcs[i + 1];
    sum += enc[(size_t)s0 * cENC + c] + enc[(size_t)s1 * cENC + c];
  }
  if (i < hi) sum += enc[(size_t)srcs[i] * cENC + c];
  float deg = (float)(hi - lo);
  agg[(size_t)n * cENC + c] = (ssc[c] * sum + deg * ssh[c]) / fmaxf(deg, 1.0f);
}

// ---------------- down-projection + BN0 stats ----------------
__global__ void k_down(const float* __restrict__ agg,
                       const float* __restrict__ z_std, const float* __restrict__ land,
                       const float* __restrict__ Wrel, const float* __restrict__ brel,
                       const float* __restrict__ Wroot,
                       float* __restrict__ x0, float* __restrict__ stats) {
  __shared__ float sstat[2 * cD];
  __shared__ float sWrel[cD * cENC], sWroot[cD * cHIGH_IN], sbrel[cD];
  int tid = threadIdx.x;
  if (tid < 2 * cD) sstat[tid] = 0.0f;
  for (int i = tid; i < cD * cENC; i += 256) sWrel[i] = Wrel[i];
  if (tid < cD * cHIGH_IN) sWroot[tid] = Wroot[tid];
  if (tid < cD) sbrel[tid] = brel[tid];
  __syncthreads();

  int n = blockIdx.x * 256 + tid;
  bool valid = n < cN_HIGH;
  float a[cENC], zz[cHIGH_IN];
  if (valid) {
    const float4* ar4 = (const float4*)(agg + (size_t)n * cENC);
    #pragma unroll
    for (int k = 0; k < cENC / 4; ++k) {
      float4 t4 = ar4[k];
      a[4*k] = t4.x; a[4*k+1] = t4.y; a[4*k+2] = t4.z; a[4*k+3] = t4.w;
    }
    #pragma unroll
    for (int k = 0; k < 6; ++k) zz[k] = z_std[(size_t)n * 6 + k];
    zz[6] = land[n];
  } else {
    #pragma unroll
    for (int k = 0; k < cENC; ++k) a[k] = 0.0f;
    #pragma unroll
    for (int k = 0; k < cHIGH_IN; ++k) zz[k] = 0.0f;
  }
  int lane = tid & 63;
  #pragma unroll
  for (int d = 0; d < cD; ++d) {
    float acc = sbrel[d];
    #pragma unroll
    for (int k = 0; k < cENC; ++k) acc += a[k] * sWrel[d * cENC + k];
    #pragma unroll
    for (int k = 0; k < cHIGH_IN; ++k) acc += zz[k] * sWroot[d * cHIGH_IN + k];
    if (valid) x0[(size_t)n * cD + d] = acc;
    float v = valid ? acc : 0.0f;
    float s1 = v, s2 = v * v;
    #pragma unroll
    for (int o = 32; o > 0; o >>= 1) { s1 += __shfl_down(s1, o); s2 += __shfl_down(s2, o); }
    if (lane == 0) { atomicAdd(&sstat[d], s1); atomicAdd(&sstat[cD + d], s2); }
  }
  __syncthreads();
  if (tid < 2 * cD) atomicAdd(&stats[tid], sstat[tid]);
}

// ---------------- GAT node transform (also emits bf16 xl rows) ----------------
__global__ void k_transform(const float* __restrict__ xin, const float* __restrict__ stats,
                            const float* __restrict__ g, const float* __restrict__ b,
                            const float* __restrict__ Wl, const float* __restrict__ bl,
                            const float* __restrict__ Wr, const float* __restrict__ br,
                            int applyRelu,
                            float* __restrict__ xl, float* __restrict__ xr,
                            unsigned short* __restrict__ xlb) {
  __shared__ float ssc[cD], ssh[cD], sWl[cD * cD], sWr[cD * cD], sbl[cD], sbr[cD];
  int tid = threadIdx.x;
  if (tid < cD) {
    float m = stats[tid] * INV_NHIGH;
    float v = stats[cD + tid] * INV_NHIGH - m * m;
    float sc = g[tid] * rsqrtf(v + cEPS);
    ssc[tid] = sc;
    ssh[tid] = b[tid] - m * sc;
    sbl[tid] = bl[tid];
    sbr[tid] = br[tid];
  }
  if (tid < cD * cD) { sWl[tid] = Wl[tid]; sWr[tid] = Wr[tid]; }
  __syncthreads();

  int n = blockIdx.x * 256 + tid;
  if (n >= cN_HIGH) return;
  float act[cD];
  const float* xp = xin + (size_t)n * cD;
  #pragma unroll
  for (int d = 0; d < cD; ++d) {
    float v = xp[d] * ssc[d] + ssh[d];
    if (applyRelu) v = fmaxf(v, 0.0f);
    act[d] = v;
  }
  float alv[cD];
  float* xlp = xl + (size_t)n * cD;
  float* xrp = xr + (size_t)n * cD;
  #pragma unroll
  for (int d = 0; d < cD; ++d) {
    float al = sbl[d], ar = sbr[d];
    #pragma unroll
    for (int k = 0; k < cD; ++k) { al += act[k] * sWl[d * cD + k]; ar += act[k] * sWr[d * cD + k]; }
    alv[d] = al;
    xlp[d] = al;
    xrp[d] = ar;
  }
  uint4 w0, w1;
  unsigned int* pw = (unsigned int*)&w0;
  #pragma unroll
  for (int k = 0; k < 4; ++k)
    pw[k] = f32_to_bf16_bits(alv[2 * k]) | (f32_to_bf16_bits(alv[2 * k + 1]) << 16);
  unsigned int* pw1 = (unsigned int*)&w1;
  #pragma unroll
  for (int k = 0; k < 4; ++k)
    pw1[k] = f32_to_bf16_bits(alv[8 + 2 * k]) | (f32_to_bf16_bits(alv[8 + 2 * k + 1]) << 16);
  uint4* dst = (uint4*)(xlb + (size_t)n * cD);
  dst[0] = w0;
  dst[1] = w1;
}

// ---------------- fused GAT edge pass: 8 lanes/node, 2 ch/lane ----------------
template<int FINAL>
__global__ __launch_bounds__(256)
void k_edge(const float* __restrict__ xl, const float* __restrict__ xr,
            const unsigned short* __restrict__ xlb,
            const int* __restrict__ rowptr, const int* __restrict__ srcs,
            const float* __restrict__ att, const float* __restrict__ bias,
            const float* __restrict__ pW, const float* __restrict__ pb,
            float* __restrict__ xout, float* __restrict__ stats,
            float* __restrict__ out) {
  __shared__ float satt[cD], sbias[cD], spw[cD];
  __shared__ float sstat[2 * cD];
  int tid = threadIdx.x;
  if (tid < cD) { satt[tid] = att[tid]; sbias[tid] = bias[tid]; spw[tid] = FINAL ? pW[tid] : 0.0f; }
  if (!FINAL && tid < 2 * cD) sstat[tid] = 0.0f;
  __syncthreads();

  int d2  = tid & 7;            // channel-pair index (channels 2*d2, 2*d2+1)
  int grp = tid >> 3;           // node within block, 0..31
  int n   = blockIdx.x * 32 + grp;
  bool valid = n < cN_HIGH;

  float a0 = satt[2 * d2], a1 = satt[2 * d2 + 1];
  float xr0 = 0.0f, xr1 = 0.0f, xs0 = 0.0f, xs1 = 0.0f;
  int lo = 0, hi = 0;
  if (valid) {
    float2 t2 = *(const float2*)(xr + (size_t)n * cD + 2 * d2);
    xr0 = t2.x; xr1 = t2.y;
    float2 t3 = *(const float2*)(xl + (size_t)n * cD + 2 * d2);
    xs0 = t3.x; xs1 = t3.y;
    lo = rowptr[n]; hi = rowptr[n + 1];
  }

  float w0 = xs0 + xr0; w0 = w0 > 0.0f ? w0 : cSLOPE * w0;
  float w1 = xs1 + xr1; w1 = w1 > 0.0f ? w1 : cSLOPE * w1;
  float pq = w0 * a0 + w1 * a1;
  pq += __shfl_xor(pq, 1); pq += __shfl_xor(pq, 2); pq += __shfl_xor(pq, 4);
  float ex = __expf(pq);
  float denom = ex;
  float num0 = ex * xs0, num1 = ex * xs1;

  const unsigned int* xlw = (const unsigned int*)xlb;
  int i = lo;
  for (; i + 3 < hi; i += 4) {
    int s0 = srcs[i], s1 = srcs[i + 1], s2 = srcs[i + 2], s3 = srcs[i + 3];
    unsigned int v0 = xlw[(size_t)s0 * 8 + d2];
    unsigned int v1 = xlw[(size_t)s1 * 8 + d2];
    unsigned int v2 = xlw[(size_t)s2 * 8 + d2];
    unsigned int v3 = xlw[(size_t)s3 * 8 + d2];
    float x00 = __uint_as_float(v0 << 16), x01 = __uint_as_float(v0 & 0xFFFF0000u);
    float x10 = __uint_as_float(v1 << 16), x11 = __uint_as_float(v1 & 0xFFFF0000u);
    float x20 = __uint_as_float(v2 << 16), x21 = __uint_as_float(v2 & 0xFFFF0000u);
    float x30 = __uint_as_float(v3 << 16), x31 = __uint_as_float(v3 & 0xFFFF0000u);
    float u00 = x00 + xr0; u00 = u00 > 0.0f ? u00 : cSLOPE * u00;
    float u01 = x01 + xr1; u01 = u01 > 0.0f ? u01 : cSLOPE * u01;
    float u10 = x10 + xr0; u10 = u10 > 0.0f ? u10 : cSLOPE * u10;
    float u11 = x11 + xr1; u11 = u11 > 0.0f ? u11 : cSLOPE * u11;
    float u20 = x20 + xr0; u20 = u20 > 0.0f ? u20 : cSLOPE * u20;
    float u21 = x21 + xr1; u21 = u21 > 0.0f ? u21 : cSLOPE * u21;
    float u30 = x30 + xr0; u30 = u30 > 0.0f ? u30 : cSLOPE * u30;
    float u31 = x31 + xr1; u31 = u31 > 0.0f ? u31 : cSLOPE * u31;
    float q0 = u00 * a0 + u01 * a1;
    float q1 = u10 * a0 + u11 * a1;
    float q2 = u20 * a0 + u21 * a1;
    float q3 = u30 * a0 + u31 * a1;
    q0 += __shfl_xor(q0, 1); q1 += __shfl_xor(q1, 1); q2 += __shfl_xor(q2, 1); q3 += __shfl_xor(q3, 1);
    q0 += __shfl_xor(q0, 2); q1 += __shfl_xor(q1, 2); q2 += __shfl_xor(q2, 2); q3 += __shfl_xor(q3, 2);
    q0 += __shfl_xor(q0, 4); q1 += __shfl_xor(q1, 4); q2 += __shfl_xor(q2, 4); q3 += __shfl_xor(q3, 4);
    float e0 = __expf(q0), e1 = __expf(q1), e2c = __expf(q2), e3 = __expf(q3);
    denom += (e0 + e1) + (e2c + e3);
    num0 += e0 * x00 + e1 * x10 + e2c * x20 + e3 * x30;
    num1 += e0 * x01 + e1 * x11 + e2c * x21 + e3 * x31;
  }
  for (; i < hi; ++i) {
    int s = srcs[i];
    unsigned int v = xlw[(size_t)s * 8 + d2];
    float x0 = __uint_as_float(v << 16), x1 = __uint_as_float(v & 0xFFFF0000u);
    float u0 = x0 + xr0; u0 = u0 > 0.0f ? u0 : cSLOPE * u0;
    float u1 = x1 + xr1; u1 = u1 > 0.0f ? u1 : cSLOPE * u1;
    float q = u0 * a0 + u1 * a1;
    q += __shfl_xor(q, 1); q += __shfl_xor(q, 2); q += __shfl_xor(q, 4);
    float e = __expf(q);
    denom += e;
    num0 += e * x0;
    num1 += e * x1;
  }
  float cnt = (float)(hi - lo + 1);
  float inv = __builtin_amdgcn_rcpf(denom * cnt);
  float res0 = num0 * inv + sbias[2 * d2];
  float res1 = num1 * inv + sbias[2 * d2 + 1];

  if (FINAL) {
    float t = fmaxf(res0, 0.0f) * spw[2 * d2] + fmaxf(res1, 0.0f) * spw[2 * d2 + 1];
    t += __shfl_xor(t, 1); t += __shfl_xor(t, 2); t += __shfl_xor(t, 4);
    if (valid && d2 == 0) out[n] = t + pb[0];
  } else {
    if (!valid) { res0 = 0.0f; res1 = 0.0f; }
    else *(float2*)(xout + (size_t)n * cD + 2 * d2) = make_float2(res0, res1);
    float s10 = res0, s11 = res1, s20 = res0 * res0, s21 = res1 * res1;
    s10 += __shfl_xor(s10, 8);  s11 += __shfl_xor(s11, 8);  s20 += __shfl_xor(s20, 8);  s21 += __shfl_xor(s21, 8);
    s10 += __shfl_xor(s10, 16); s11 += __shfl_xor(s11, 16); s20 += __shfl_xor(s20, 16); s21 += __shfl_xor(s21, 16);
    s10 += __shfl_xor(s10, 32); s11 += __shfl_xor(s11, 32); s20 += __shfl_xor(s20, 32); s21 += __shfl_xor(s21, 32);
    if ((tid & 63) < 8) {
      atomicAdd(&sstat[2 * d2], s10);
      atomicAdd(&sstat[2 * d2 + 1], s11);
      atomicAdd(&sstat[cD + 2 * d2], s20);
      atomicAdd(&sstat[cD + 2 * d2 + 1], s21);
    }
    __syncthreads();
    if (tid < 2 * cD) atomicAdd(&stats[tid], sstat[tid]);
  }
}

// ---------------- launch ----------------
extern "C" void kernel_launch(void* const* d_in, const int* in_sizes, int n_in,
                              void* d_out, int out_size, void* d_ws, size_t ws_size,
                              hipStream_t stream) {
  const float* x_low    = (const float*)d_in[0];
  const float* z_std    = (const float*)d_in[1];
  const float* land     = (const float*)d_in[2];
  const int*   l2h_src  = (const int*)d_in[3];
  const int*   l2h_dst  = (const int*)d_in[4];
  const int*   hh_src   = (const int*)d_in[5];
  const int*   hh_dst   = (const int*)d_in[6];
  const float* gWih     = (const float*)d_in[7];
  const float* gWhh     = (const float*)d_in[8];
  const float* gbih     = (const float*)d_in[9];
  const float* gbhh     = (const float*)d_in[10];
  const float* dW       = (const float*)d_in[11];
  const float* db       = (const float*)d_in[12];
  const float* bn_enc_g = (const float*)d_in[13];
  const float* bn_enc_b = (const float*)d_in[14];
  const float* Wrel     = (const float*)d_in[15];
  const float* brel     = (const float*)d_in[16];
  const float* Wroot    = (const float*)d_in[17];
  const float* gat_Wl   = (const float*)d_in[18];
  const float* gat_bl   = (const float*)d_in[19];
  const float* gat_Wr   = (const float*)d_in[20];
  const float* gat_br   = (const float*)d_in[21];
  const float* gat_att  = (const float*)d_in[22];
  const float* gat_bias = (const float*)d_in[23];
  const float* bn_g     = (const float*)d_in[24];
  const float* bn_b     = (const float*)d_in[25];
  const float* pred_W   = (const float*)d_in[26];
  const float* pred_b   = (const float*)d_in[27];

  float* ws = (float*)d_ws;
  float* hs   = ws + OFF_HS;
  float* agg  = ws + OFF_AGG;
  float* enc  = ws + OFF_ENC;
  float* xA   = ws + OFF_XA;
  float* xB   = ws + OFF_XB;
  float* xl   = ws + OFF_XL;
  float* xr   = ws + OFF_XR;
  float* statsEnc = ws + OFF_STAT;
  float* statsX   = ws + OFF_STAT + 64;
  int* rp_hh  = (int*)(ws + OFF_RPH);
  int* src_hh = (int*)(ws + OFF_SRH);
  int* rp_l2h = (int*)(ws + OFF_RPL);
  int* src_l2h= (int*)(ws + OFF_SRL);
  int* cursor = (int*)(ws + OFF_CUR);
  int* part   = (int*)(ws + OFF_PART);
  unsigned short* xlb = (unsigned short*)(ws + OFF_XLB);

  hipMemsetAsync(statsEnc, 0, 256 * sizeof(float), stream);

  // --- CSR build: hh ---
  hipMemsetAsync(cursor, 0, cN_HIGH * sizeof(int), stream);
  k_hist<<<(cE_HH + 255) / 256, 256, 0, stream>>>(hh_dst, cE_HH, cursor);
  k_scan_local<<<SC_NB, 256, 0, stream>>>(cursor, cN_HIGH, rp_hh, part);
  k_scan_top<<<1, 256, 0, stream>>>(part, SC_NB, rp_hh + cN_HIGH);
  k_scan_add<<<SC_NB, 256, 0, stream>>>(rp_hh, part, cN_HIGH, cursor);
  k_scatter<<<(cE_HH + 255) / 256, 256, 0, stream>>>(hh_src, hh_dst, cE_HH, cursor, src_hh);
  // --- CSR build: l2h ---
  hipMemsetAsync(cursor, 0, cN_HIGH * sizeof(int), stream);
  k_hist<<<(cE_L2H + 255) / 256, 256, 0, stream>>>(l2h_dst, cE_L2H, cursor);
  k_scan_local<<<SC_NB, 256, 0, stream>>>(cursor, cN_HIGH, rp_l2h, part);
  k_scan_top<<<1, 256, 0, stream>>>(part, SC_NB, rp_l2h + cN_HIGH);
  k_scan_add<<<SC_NB, 256, 0, stream>>>(rp_l2h, part, cN_HIGH, cursor);
  k_scatter<<<(cE_L2H + 255) / 256, 256, 0, stream>>>(l2h_src, l2h_dst, cE_L2H, cursor, src_l2h);

  // --- encoder ---
  k_gru<<<cN_LOW / GN, GB, 0, stream>>>(x_low, gWih, gWhh, gbih, gbhh, hs);
  k_dense<<<cN_LOW / cDN, 256, 0, stream>>>(hs, dW, db, enc, statsEnc);
  k_gather_csr<<<cN_HIGH / 8, 256, 0, stream>>>(enc, rp_l2h, src_l2h, statsEnc,
                                                bn_enc_g, bn_enc_b, agg);
  const int NODE_GRID = (cN_HIGH + 255) / 256;
  k_down<<<NODE_GRID, 256, 0, stream>>>(agg, z_std, land, Wrel, brel, Wroot, xA, statsX);

  const int EDGE_GRID = (cN_HIGH + 31) / 32;
  // --- 5 GATv2 layers ---
  for (int i = 0; i < cNL; ++i) {
    float* xin  = (i & 1) ? xB : xA;
    float* xout = (i & 1) ? xA : xB;
    k_transform<<<NODE_GRID, 256, 0, stream>>>(xin, statsX + 32 * i,
                                               bn_g + 16 * i, bn_b + 16 * i,
                                               gat_Wl + 256 * i, gat_bl + 16 * i,
                                               gat_Wr + 256 * i, gat_br + 16 * i,
                                               (i > 0) ? 1 : 0, xl, xr, xlb);
    if (i < cNL - 1) {
      k_edge<0><<<EDGE_GRID, 256, 0, stream>>>(xl, xr, xlb, rp_hh, src_hh,
                                               gat_att + 16 * i, gat_bias + 16 * i,
                                               nullptr, nullptr,
                                               xout, statsX + 32 * (i + 1), nullptr);
    } else {
      k_edge<1><<<EDGE_GRID, 256, 0, stream>>>(xl, xr, xlb, rp_hh, src_hh,
                                               gat_att + 16 * i, gat_bias + 16 * i,
                                               pred_W, pred_b,
                                               nullptr, nullptr, (float*)d_out);
    }
  }
}